// Round 13
// baseline (226.284 us; speedup 1.0000x reference)
//
#include <hip/hip_runtime.h>
#include <stdint.h>

typedef _Float16 v8h __attribute__((ext_vector_type(8)));
typedef _Float16 v2h __attribute__((ext_vector_type(2)));
typedef float v4f __attribute__((ext_vector_type(4)));
typedef float v16f __attribute__((ext_vector_type(16)));

#define NPTS 2048
#define BATCH 16
#define KNN 20
#define PAIRS (NPTS * KNN)   // 40960 per batch

// ---------- helpers ----------
__device__ __forceinline__ unsigned pair_relu_h2(unsigned pu, unsigned qu) {
  v2h a = *(const v2h*)&pu;
  v2h b = *(const v2h*)&qu;
  v2h s = a + b;                                   // v_pk_add_f16
  v2h z = {(_Float16)0.f, (_Float16)0.f};
  v2h r = __builtin_elementwise_max(s, z);         // v_pk_max_f16 (relu)
  return *(const unsigned*)&r;
}
__device__ __forceinline__ float fmax3(float a, float b, float c) {
  return fmaxf(fmaxf(a, b), c);                    // fuses to v_max3_f32
}

// ---------- K1: fused exact-20NN + prep(M2, in LDS) + pq emission + H zero ----------
// R17: M2 computed once per block into LDS (R16's per-thread fold cost +18us).
// R10 knn core: norm-trick distances, 8 q/wave, 64-slot rank-count select.
__global__ __launch_bounds__(512, 2) void knn_kernel(
    const float* __restrict__ x, int* __restrict__ idxOut,
    const float* __restrict__ W1, const float* __restrict__ W2,
    unsigned short* __restrict__ p, unsigned short* __restrict__ q,
    int* __restrict__ H) {
  __shared__ float4 pts[NPTS];                    // 32 KB (x,y,z,|.|^2)
  __shared__ unsigned long long cand[8][8][64];   // 32 KB, wave-private
  __shared__ float M2s[128][6];                   // 3 KB: [ch][a0..2 | b0..2]
  int b = blockIdx.x >> 5;
  int qblk = blockIdx.x & 31;
  const float* xb = x + b * 3 * NPTS;

  if (qblk == 0 && threadIdx.x < 256) H[b * 256 + threadIdx.x] = 0;

  for (int i = threadIdx.x; i < NPTS; i += 512) {
    float X = xb[i], Y = xb[NPTS + i], Z = xb[2 * NPTS + i];
    pts[i] = make_float4(X, Y, Z, X * X + Y * Y + Z * Z);
  }

  // M2 once per block: thread o (<128) computes channel o's 6 coefficients.
  if (threadIdx.x < 128) {
    int o = threadIdx.x;
    const float* w2 = W2 + o * 64;
    float a0 = 0, a1 = 0, a2 = 0, a3 = 0, a4 = 0, a5 = 0;
    for (int i = 0; i < 64; ++i) {
      const float* w1r = W1 + i * 6;
      float w = w2[i];
      a0 += w * w1r[0]; a1 += w * w1r[1]; a2 += w * w1r[2];
      a3 += w * (w1r[3] - w1r[0]); a4 += w * (w1r[4] - w1r[1]); a5 += w * (w1r[5] - w1r[2]);
    }
    M2s[o][0] = a0; M2s[o][1] = a1; M2s[o][2] = a2;
    M2s[o][3] = a3; M2s[o][4] = a4; M2s[o][5] = a5;
  }
  __syncthreads();

  int wid = threadIdx.x >> 6, lane = threadIdx.x & 63;
  int qbase = qblk * 64 + wid * 8;                // 8 queries per wave

  // pq fold: emit p/q rows for this wave's 8 queries (coalesced stores).
  {
    int o0 = lane * 2;
    float a0 = M2s[o0][0], a1 = M2s[o0][1], a2 = M2s[o0][2];
    float a3 = M2s[o0][3], a4 = M2s[o0][4], a5 = M2s[o0][5];
    float c0 = M2s[o0 + 1][0], c1 = M2s[o0 + 1][1], c2 = M2s[o0 + 1][2];
    float c3 = M2s[o0 + 1][3], c4 = M2s[o0 + 1][4], c5 = M2s[o0 + 1][5];
    unsigned* pw = (unsigned*)p;
    unsigned* qw = (unsigned*)q;
#pragma unroll
    for (int g = 0; g < 8; ++g) {
      int j = qbase + g;
      float4 qp = pts[j];                         // broadcast LDS read
      float p0 = a0 * qp.x + a1 * qp.y + a2 * qp.z;
      float p1 = c0 * qp.x + c1 * qp.y + c2 * qp.z;
      float q0 = a3 * qp.x + a4 * qp.y + a5 * qp.z;
      float q1 = c3 * qp.x + c4 * qp.y + c5 * qp.z;
      size_t base = ((size_t)(b * NPTS + j)) * 64 + lane;
      auto hp = __builtin_amdgcn_cvt_pkrtz(p0, p1);
      auto hq = __builtin_amdgcn_cvt_pkrtz(q0, q1);
      pw[base] = *(const unsigned*)&hp;
      qw[base] = *(const unsigned*)&hq;
    }
  }

  float m2x[8], m2y[8], m2z[8], mn[8];
#pragma unroll
  for (int g = 0; g < 8; ++g) {
    float4 qp = pts[qbase + g];                   // broadcast read
    m2x[g] = -2.f * qp.x; m2y[g] = -2.f * qp.y; m2z[g] = -2.f * qp.z;
    mn[g] = 1e30f;
  }

  // pass 1: per-lane min over its 32 points, all 8 queries share the load
  for (int s = 0; s < 32; ++s) {
    float4 P = pts[s * 64 + lane];
#pragma unroll
    for (int g = 0; g < 8; ++g) {
      float d = fmaf(m2x[g], P.x, fmaf(m2y[g], P.y, fmaf(m2z[g], P.z, P.w)));
      mn[g] = fminf(mn[g], d);
    }
  }

  // tau[g] = 20th-smallest lane-min (upper bound on d'_(20)), inflated
  float tau[8];
#pragma unroll
  for (int g = 0; g < 8; ++g) {
    float v = mn[g];
    for (int k = 2; k <= 64; k <<= 1) {
      for (int j = k >> 1; j > 0; j >>= 1) {
        float o = __shfl_xor(v, j);
        bool low = (lane & j) == 0;
        bool up = (lane & k) == 0;
        v = (low == up) ? fminf(v, o) : fmaxf(v, o);
      }
    }
    float t = __shfl(v, 19);
    tau[g] = t + fabsf(t) * 4e-6f + 1e-6f;
  }

  // pass 2: recompute, ballot-compact candidates per query
  int cnt[8] = {0, 0, 0, 0, 0, 0, 0, 0};
  for (int s = 0; s < 32; ++s) {
    int i = s * 64 + lane;
    float4 P = pts[i];
#pragma unroll
    for (int g = 0; g < 8; ++g) {
      float d = fmaf(m2x[g], P.x, fmaf(m2y[g], P.y, fmaf(m2z[g], P.z, P.w)));
      bool take = d <= tau[g];
      unsigned long long mb = __ballot(take);
      if (take) {
        int pos = cnt[g] + __popcll(mb & ((1ull << lane) - 1ull));
        if (pos < 64) {
          unsigned kd = __float_as_uint(d + 64.f);   // d > -64: monotone key
          cand[wid][g][pos] = (((unsigned long long)kd) << 32) | (unsigned)i;
        }
      }
      cnt[g] += __popcll(mb);
    }
  }
  // cand written & read by the same wave: no __syncthreads needed.

  // rank-count select: broadcast reads; keys unique (index tiebreak).
#pragma unroll
  for (int g = 0; g < 8; ++g) {
    int nc = cnt[g] < 64 ? cnt[g] : 64;
    unsigned long long k0 = (lane < nc) ? cand[wid][g][lane] : ~0ull;
    int r0 = 0;
    for (int i = 0; i < nc; ++i) r0 += (cand[wid][g][i] < k0) ? 1 : 0;
    long long obase = ((long long)b * NPTS + qbase + g) * KNN;
    if (lane < nc && r0 < KNN) idxOut[obase + r0] = (int)(k0 & 0xffffffffu);
  }
}

// ---------- K2: h3 = relu(W3 · relu(p_j+q_n)), producer-consumer waves ----------
// R18: MfmaUtil pinned at 33% across SIX lockstep variants -> waves convoy
// through the shared stage/barrier cadence. Fix: wave specialization.
// 384-thr blocks: waves 0-1 = PRODUCERS (gather p/q, pair-relu, swizzled
// ds_write into a 6-slot ring), waves 2-5 = CONSUMERS (one 64-ch group
// each: poll flag -> 8 ds_read_b128 -> 16 MFMA -> max3). NO __syncthreads
// in the loop; monotonic LDS flags (no ABA, no resets):
//   producers: ready0/1[slot] = s (release, lane 0 - wave-level s_waitcnt
//              covers all lanes' ds_writes);
//   consumers: used[slot] += 1 (release, after reads);
//   producer reuse gate: used[slot] >= 4*(s/RING).
// Consumer issue/tile ~650 cyc of which 512 matrix -> per-wave density 75%.
// Grid 512 = 2 blocks/CU (LDS 49KB); batch->XCD pin kept (b = blockIdx&15).
__global__ __launch_bounds__(384) void gemm_max_kernel(
    const unsigned short* __restrict__ p, const unsigned short* __restrict__ q,
    const int* __restrict__ idx, const float* __restrict__ W3, int* __restrict__ H) {
#define RING 6
#define NTIL 40                               // 1280 tiles / 32 blocks-per-batch
  __shared__ __align__(16) unsigned short tile[RING][32 * 128];  // 48 KB
  __shared__ int ready0[RING], ready1[RING], used[RING];

  int b = blockIdx.x & 15;
  int w = blockIdx.x >> 4;                    // 0..31
  int t = threadIdx.x;                        // 0..383
  int wid = t >> 6, lane = t & 63;

  if (t < RING) { ready0[t] = -1; ready1[t] = -1; used[t] = 0; }
  __syncthreads();                            // once, before role divergence

  const unsigned short* pB = p + (size_t)b * NPTS * 128;
  const unsigned short* qB = q + (size_t)b * NPTS * 128;
  const int* idxB = idx + (size_t)b * PAIRS;

  if (wid < 2) {
    // ---- PRODUCER (2 waves jointly stage each tile) ----
    int plane = wid * 64 + lane;              // 0..127
    int pair = plane >> 2;                    // 0..31
    int quarter = plane & 3;                  // 64B of p-row + 64B of q-row
    // swizzled store offsets (shorts): unit u = quarter*4+k -> u ^ (pair&7)
    int stoff[4];
#pragma unroll
    for (int k = 0; k < 4; ++k)
      stoff[k] = pair * 128 + (((quarter * 4 + k) ^ (pair & 7)) * 8);

    uint4 P[2][4], Q[2][4];                   // 2-deep pipeline
#pragma unroll
    for (int s0 = 0; s0 < 2; ++s0) {
      int pr = (w + s0 * 32) * 32 + pair;
      int j = idxB[pr] & (NPTS - 1);
      unsigned n = (unsigned)pr / 20u;
#pragma unroll
      for (int k = 0; k < 4; ++k) {
        P[s0][k] = *(const uint4*)(pB + (size_t)j * 128 + quarter * 32 + k * 8);
        Q[s0][k] = *(const uint4*)(qB + (size_t)n * 128 + quarter * 32 + k * 8);
      }
    }
    for (int s = 0; s < NTIL; ++s) {
      int slot = s - (s / RING) * RING;
      int e = s / RING;
      if (e > 0) {                            // wait all 4 consumers done with slot
        while (__hip_atomic_load(&used[slot], __ATOMIC_ACQUIRE,
                                 __HIP_MEMORY_SCOPE_WORKGROUP) < 4 * e)
          __builtin_amdgcn_s_sleep(2);
      }
      int d = s & 1;
#pragma unroll
      for (int k = 0; k < 4; ++k) {
        uint4 R;
        R.x = pair_relu_h2(P[d][k].x, Q[d][k].x);
        R.y = pair_relu_h2(P[d][k].y, Q[d][k].y);
        R.z = pair_relu_h2(P[d][k].z, Q[d][k].z);
        R.w = pair_relu_h2(P[d][k].w, Q[d][k].w);
        *(uint4*)&tile[slot][stoff[k]] = R;
      }
      if (lane == 0) {                        // release: waits this wave's ds_writes
        if (wid == 0)
          __hip_atomic_store(&ready0[slot], s, __ATOMIC_RELEASE, __HIP_MEMORY_SCOPE_WORKGROUP);
        else
          __hip_atomic_store(&ready1[slot], s, __ATOMIC_RELEASE, __HIP_MEMORY_SCOPE_WORKGROUP);
      }
      int sn = s + 2;
      if (sn < NTIL) {                        // refill pipeline depth-2
        int pr = (w + sn * 32) * 32 + pair;
        int j = idxB[pr] & (NPTS - 1);
        unsigned n = (unsigned)pr / 20u;
#pragma unroll
        for (int k = 0; k < 4; ++k) {
          P[d][k] = *(const uint4*)(pB + (size_t)j * 128 + quarter * 32 + k * 8);
          Q[d][k] = *(const uint4*)(qB + (size_t)n * 128 + quarter * 32 + k * 8);
        }
      }
    }
  } else {
    // ---- CONSUMER (wave cg owns channels [cg*64, cg*64+64)) ----
    int cg = wid - 2;
    int col = lane & 31, hi = lane >> 5;
    v8h bfr0[8], bfr1[8];
#pragma unroll
    for (int kk = 0; kk < 8; ++kk) {
      const float* s0 = W3 + (size_t)(cg * 64 + col) * 128 + kk * 16 + hi * 8;
      const float* s1 = s0 + 32 * 128;
      v8h f0, f1;
#pragma unroll
      for (int jj = 0; jj < 8; ++jj) { f0[jj] = (_Float16)s0[jj]; f1[jj] = (_Float16)s1[jj]; }
      bfr0[kk] = f0; bfr1[kk] = f1;
    }

    float vmx0 = 0.f, vmx1 = 0.f;
    for (int s = 0; s < NTIL; ++s) {
      int slot = s - (s / RING) * RING;
      while (__hip_atomic_load(&ready0[slot], __ATOMIC_ACQUIRE,
                               __HIP_MEMORY_SCOPE_WORKGROUP) < s ||
             __hip_atomic_load(&ready1[slot], __ATOMIC_ACQUIRE,
                               __HIP_MEMORY_SCOPE_WORKGROUP) < s)
        __builtin_amdgcn_s_sleep(2);

      v16f acc0 = {0.f}, acc1 = {0.f};
#pragma unroll
      for (int kk = 0; kk < 8; ++kk) {
        v8h a = *(const v8h*)&tile[slot][col * 128 + (((kk * 2 + hi) ^ (col & 7)) * 8)];
        acc0 = __builtin_amdgcn_mfma_f32_32x32x16_f16(a, bfr0[kk], acc0, 0, 0, 0);
        acc1 = __builtin_amdgcn_mfma_f32_32x32x16_f16(a, bfr1[kk], acc1, 0, 0, 0);
      }
      if (lane == 0)                          // release: waits this wave's ds_reads
        __hip_atomic_fetch_add(&used[slot], 1, __ATOMIC_RELEASE, __HIP_MEMORY_SCOPE_WORKGROUP);

      float m0 = fmax3(acc0[0], acc0[1], acc0[2]);
      float m1 = fmax3(acc0[3], acc0[4], acc0[5]);
      float m2 = fmax3(acc0[6], acc0[7], acc0[8]);
      float m3 = fmax3(acc0[9], acc0[10], acc0[11]);
      float m4 = fmax3(acc0[12], acc0[13], acc0[14]);
      vmx0 = fmax3(fmax3(m0, m1, m2), fmax3(m3, m4, acc0[15]), vmx0);
      float n0 = fmax3(acc1[0], acc1[1], acc1[2]);
      float n1 = fmax3(acc1[3], acc1[4], acc1[5]);
      float n2 = fmax3(acc1[6], acc1[7], acc1[8]);
      float n3 = fmax3(acc1[9], acc1[10], acc1[11]);
      float n4 = fmax3(acc1[12], acc1[13], acc1[14]);
      vmx1 = fmax3(fmax3(n0, n1, n2), fmax3(n3, n4, acc1[15]), vmx1);
    }

    // lanes l and l^32 hold the same channel: reduce, write
    float v0 = fmaxf(vmx0, __shfl_xor(vmx0, 32));
    float v1 = fmaxf(vmx1, __shfl_xor(vmx1, 32));
    if (hi == 0) {
      atomicMax(&H[b * 256 + cg * 64 + col], __float_as_int(v0));
      atomicMax(&H[b * 256 + cg * 64 + 32 + col], __float_as_int(v1));
    }
  }
#undef RING
#undef NTIL
}

// ---------- K3: out = H @ fc_w^T + fc_b (one wave per output element) ----------
__global__ __launch_bounds__(64) void fc_kernel(const int* __restrict__ Hi,
                                                const float* __restrict__ fcw,
                                                const float* __restrict__ fcb,
                                                float* __restrict__ out) {
  int b = blockIdx.x / 10, r = blockIdx.x % 10;
  int lane = threadIdx.x;
  const float* Hb = (const float*)Hi + b * 256;
  float s = 0.f;
#pragma unroll
  for (int c = lane; c < 256; c += 64) s += Hb[c] * fcw[r * 256 + c];
#pragma unroll
  for (int m = 32; m > 0; m >>= 1) s += __shfl_xor(s, m);
  if (lane == 0) out[b * 10 + r] = s + fcb[r];
}

// ---------- launch ----------
extern "C" void kernel_launch(void* const* d_in, const int* in_sizes, int n_in,
                              void* d_out, int out_size, void* d_ws, size_t ws_size,
                              hipStream_t stream) {
  const float* x   = (const float*)d_in[0];
  const float* W1  = (const float*)d_in[1];
  const float* W2  = (const float*)d_in[2];
  const float* W3  = (const float*)d_in[3];
  const float* fcw = (const float*)d_in[4];
  const float* fcb = (const float*)d_in[5];
  float* out = (float*)d_out;
  char* ws = (char*)d_ws;

  // workspace layout (needs ~20 MB)
  int* H     = (int*)(ws + 4096);           // 16 KB (16x256 f32-as-int)
  int* idx   = (int*)(ws + 24576);          // 2.62 MB
  unsigned short* p = (unsigned short*)(ws + 3145728);   // 8.39 MB fp16
  unsigned short* q = (unsigned short*)(ws + 12582912);  // 8.39 MB fp16

  knn_kernel<<<BATCH * 32, 512, 0, stream>>>(x, idx, W1, W2, p, q, H);
  gemm_max_kernel<<<BATCH * 32, 384, 0, stream>>>(p, q, idx, W3, H);
  fc_kernel<<<BATCH * 10, 64, 0, stream>>>(H, fcw, fcb, out);
}

// Round 14
// 225.892 us; speedup vs baseline: 1.0017x; 1.0017x over previous
//
#include <hip/hip_runtime.h>
#include <stdint.h>

typedef _Float16 v8h __attribute__((ext_vector_type(8)));
typedef _Float16 v2h __attribute__((ext_vector_type(2)));
typedef float v4f __attribute__((ext_vector_type(4)));
typedef float v16f __attribute__((ext_vector_type(16)));

#define NPTS 2048
#define BATCH 16
#define KNN 20
#define PAIRS (NPTS * KNN)   // 40960 per batch

// ---------- helpers ----------
__device__ __forceinline__ unsigned pair_relu_h2(unsigned pu, unsigned qu) {
  v2h a = *(const v2h*)&pu;
  v2h b = *(const v2h*)&qu;
  v2h s = a + b;                                   // v_pk_add_f16
  v2h z = {(_Float16)0.f, (_Float16)0.f};
  v2h r = __builtin_elementwise_max(s, z);         // v_pk_max_f16 (relu)
  return *(const unsigned*)&r;
}
__device__ __forceinline__ float fmax3(float a, float b, float c) {
  return fmaxf(fmaxf(a, b), c);                    // fuses to v_max3_f32
}

// ---------- K1: fused exact-20NN + prep(M2, in LDS) + pq emission + H zero ----------
// R17: M2 computed once per block into LDS (R16's per-thread fold cost +18us).
// R10 knn core: norm-trick distances, 8 q/wave, 64-slot rank-count select.
__global__ __launch_bounds__(512, 2) void knn_kernel(
    const float* __restrict__ x, int* __restrict__ idxOut,
    const float* __restrict__ W1, const float* __restrict__ W2,
    unsigned short* __restrict__ p, unsigned short* __restrict__ q,
    int* __restrict__ H) {
  __shared__ float4 pts[NPTS];                    // 32 KB (x,y,z,|.|^2)
  __shared__ unsigned long long cand[8][8][64];   // 32 KB, wave-private
  __shared__ float M2s[128][6];                   // 3 KB: [ch][a0..2 | b0..2]
  int b = blockIdx.x >> 5;
  int qblk = blockIdx.x & 31;
  const float* xb = x + b * 3 * NPTS;

  if (qblk == 0 && threadIdx.x < 256) H[b * 256 + threadIdx.x] = 0;

  for (int i = threadIdx.x; i < NPTS; i += 512) {
    float X = xb[i], Y = xb[NPTS + i], Z = xb[2 * NPTS + i];
    pts[i] = make_float4(X, Y, Z, X * X + Y * Y + Z * Z);
  }

  // M2 once per block: thread o (<128) computes channel o's 6 coefficients.
  if (threadIdx.x < 128) {
    int o = threadIdx.x;
    const float* w2 = W2 + o * 64;
    float a0 = 0, a1 = 0, a2 = 0, a3 = 0, a4 = 0, a5 = 0;
    for (int i = 0; i < 64; ++i) {
      const float* w1r = W1 + i * 6;
      float w = w2[i];
      a0 += w * w1r[0]; a1 += w * w1r[1]; a2 += w * w1r[2];
      a3 += w * (w1r[3] - w1r[0]); a4 += w * (w1r[4] - w1r[1]); a5 += w * (w1r[5] - w1r[2]);
    }
    M2s[o][0] = a0; M2s[o][1] = a1; M2s[o][2] = a2;
    M2s[o][3] = a3; M2s[o][4] = a4; M2s[o][5] = a5;
  }
  __syncthreads();

  int wid = threadIdx.x >> 6, lane = threadIdx.x & 63;
  int qbase = qblk * 64 + wid * 8;                // 8 queries per wave

  // pq fold: emit p/q rows for this wave's 8 queries (coalesced stores).
  {
    int o0 = lane * 2;
    float a0 = M2s[o0][0], a1 = M2s[o0][1], a2 = M2s[o0][2];
    float a3 = M2s[o0][3], a4 = M2s[o0][4], a5 = M2s[o0][5];
    float c0 = M2s[o0 + 1][0], c1 = M2s[o0 + 1][1], c2 = M2s[o0 + 1][2];
    float c3 = M2s[o0 + 1][3], c4 = M2s[o0 + 1][4], c5 = M2s[o0 + 1][5];
    unsigned* pw = (unsigned*)p;
    unsigned* qw = (unsigned*)q;
#pragma unroll
    for (int g = 0; g < 8; ++g) {
      int j = qbase + g;
      float4 qp = pts[j];                         // broadcast LDS read
      float p0 = a0 * qp.x + a1 * qp.y + a2 * qp.z;
      float p1 = c0 * qp.x + c1 * qp.y + c2 * qp.z;
      float q0 = a3 * qp.x + a4 * qp.y + a5 * qp.z;
      float q1 = c3 * qp.x + c4 * qp.y + c5 * qp.z;
      size_t base = ((size_t)(b * NPTS + j)) * 64 + lane;
      auto hp = __builtin_amdgcn_cvt_pkrtz(p0, p1);
      auto hq = __builtin_amdgcn_cvt_pkrtz(q0, q1);
      pw[base] = *(const unsigned*)&hp;
      qw[base] = *(const unsigned*)&hq;
    }
  }

  float m2x[8], m2y[8], m2z[8], mn[8];
#pragma unroll
  for (int g = 0; g < 8; ++g) {
    float4 qp = pts[qbase + g];                   // broadcast read
    m2x[g] = -2.f * qp.x; m2y[g] = -2.f * qp.y; m2z[g] = -2.f * qp.z;
    mn[g] = 1e30f;
  }

  // pass 1: per-lane min over its 32 points, all 8 queries share the load
  for (int s = 0; s < 32; ++s) {
    float4 P = pts[s * 64 + lane];
#pragma unroll
    for (int g = 0; g < 8; ++g) {
      float d = fmaf(m2x[g], P.x, fmaf(m2y[g], P.y, fmaf(m2z[g], P.z, P.w)));
      mn[g] = fminf(mn[g], d);
    }
  }

  // tau[g] = 20th-smallest lane-min (upper bound on d'_(20)), inflated
  float tau[8];
#pragma unroll
  for (int g = 0; g < 8; ++g) {
    float v = mn[g];
    for (int k = 2; k <= 64; k <<= 1) {
      for (int j = k >> 1; j > 0; j >>= 1) {
        float o = __shfl_xor(v, j);
        bool low = (lane & j) == 0;
        bool up = (lane & k) == 0;
        v = (low == up) ? fminf(v, o) : fmaxf(v, o);
      }
    }
    float t = __shfl(v, 19);
    tau[g] = t + fabsf(t) * 4e-6f + 1e-6f;
  }

  // pass 2: recompute, ballot-compact candidates per query
  int cnt[8] = {0, 0, 0, 0, 0, 0, 0, 0};
  for (int s = 0; s < 32; ++s) {
    int i = s * 64 + lane;
    float4 P = pts[i];
#pragma unroll
    for (int g = 0; g < 8; ++g) {
      float d = fmaf(m2x[g], P.x, fmaf(m2y[g], P.y, fmaf(m2z[g], P.z, P.w)));
      bool take = d <= tau[g];
      unsigned long long mb = __ballot(take);
      if (take) {
        int pos = cnt[g] + __popcll(mb & ((1ull << lane) - 1ull));
        if (pos < 64) {
          unsigned kd = __float_as_uint(d + 64.f);   // d > -64: monotone key
          cand[wid][g][pos] = (((unsigned long long)kd) << 32) | (unsigned)i;
        }
      }
      cnt[g] += __popcll(mb);
    }
  }
  // cand written & read by the same wave: no __syncthreads needed.

  // rank-count select: broadcast reads; keys unique (index tiebreak).
#pragma unroll
  for (int g = 0; g < 8; ++g) {
    int nc = cnt[g] < 64 ? cnt[g] : 64;
    unsigned long long k0 = (lane < nc) ? cand[wid][g][lane] : ~0ull;
    int r0 = 0;
    for (int i = 0; i < nc; ++i) r0 += (cand[wid][g][i] < k0) ? 1 : 0;
    long long obase = ((long long)b * NPTS + qbase + g) * KNN;
    if (lane < nc && r0 < KNN) idxOut[obase + r0] = (int)(k0 & 0xffffffffu);
  }
}

// ---------- K2: h3 = relu(W3 · relu(p_j+q_n)), producer-consumer waves ----------
// R19 = R18 with the register budget pinned. R18's 122us was the R11 spill
// signature (VGPR capped at 72 by the compiler's default occupancy
// heuristic, WRITE_SIZE 1MB->28MB scratch): the specialization hypothesis
// was never tested. __launch_bounds__(384, 2) -> VGPR cap 256, natural
// ~130 fits, no spill. TRIPWIRE: VGPR must read 110-170 and WRITE ~1MB;
// if VGPR<=80 or WRITE>>1MB, experiment void -> revert gemm to R14.
// Protocol (verified correct in R18's passing run): waves 0-1 producers
// (gather p/q, pair-relu, swizzled ds_write, 6-slot ring), waves 2-5
// consumers (poll -> 8 ds_read_b128 -> 16 MFMA -> max3). Monotonic LDS
// flags, no __syncthreads in loop, no ABA.
__global__ __launch_bounds__(384, 2) void gemm_max_kernel(
    const unsigned short* __restrict__ p, const unsigned short* __restrict__ q,
    const int* __restrict__ idx, const float* __restrict__ W3, int* __restrict__ H) {
#define RING 6
#define NTIL 40                               // 1280 tiles / 32 blocks-per-batch
  __shared__ __align__(16) unsigned short tile[RING][32 * 128];  // 48 KB
  __shared__ int ready0[RING], ready1[RING], used[RING];

  int b = blockIdx.x & 15;
  int w = blockIdx.x >> 4;                    // 0..31
  int t = threadIdx.x;                        // 0..383
  int wid = t >> 6, lane = t & 63;

  if (t < RING) { ready0[t] = -1; ready1[t] = -1; used[t] = 0; }
  __syncthreads();                            // once, before role divergence

  const unsigned short* pB = p + (size_t)b * NPTS * 128;
  const unsigned short* qB = q + (size_t)b * NPTS * 128;
  const int* idxB = idx + (size_t)b * PAIRS;

  if (wid < 2) {
    // ---- PRODUCER (2 waves jointly stage each tile) ----
    int plane = wid * 64 + lane;              // 0..127
    int pair = plane >> 2;                    // 0..31
    int quarter = plane & 3;                  // 64B of p-row + 64B of q-row
    // swizzled store offsets (shorts): unit u = quarter*4+k -> u ^ (pair&7)
    int stoff[4];
#pragma unroll
    for (int k = 0; k < 4; ++k)
      stoff[k] = pair * 128 + (((quarter * 4 + k) ^ (pair & 7)) * 8);

    uint4 P[2][4], Q[2][4];                   // 2-deep pipeline
#pragma unroll
    for (int s0 = 0; s0 < 2; ++s0) {
      int pr = (w + s0 * 32) * 32 + pair;
      int j = idxB[pr] & (NPTS - 1);
      unsigned n = (unsigned)pr / 20u;
#pragma unroll
      for (int k = 0; k < 4; ++k) {
        P[s0][k] = *(const uint4*)(pB + (size_t)j * 128 + quarter * 32 + k * 8);
        Q[s0][k] = *(const uint4*)(qB + (size_t)n * 128 + quarter * 32 + k * 8);
      }
    }
    for (int s = 0; s < NTIL; ++s) {
      int slot = s - (s / RING) * RING;
      int e = s / RING;
      if (e > 0) {                            // wait all 4 consumers done with slot
        while (__hip_atomic_load(&used[slot], __ATOMIC_ACQUIRE,
                                 __HIP_MEMORY_SCOPE_WORKGROUP) < 4 * e)
          __builtin_amdgcn_s_sleep(2);
      }
      int d = s & 1;
#pragma unroll
      for (int k = 0; k < 4; ++k) {
        uint4 R;
        R.x = pair_relu_h2(P[d][k].x, Q[d][k].x);
        R.y = pair_relu_h2(P[d][k].y, Q[d][k].y);
        R.z = pair_relu_h2(P[d][k].z, Q[d][k].z);
        R.w = pair_relu_h2(P[d][k].w, Q[d][k].w);
        *(uint4*)&tile[slot][stoff[k]] = R;
      }
      if (lane == 0) {                        // release: waits this wave's ds_writes
        if (wid == 0)
          __hip_atomic_store(&ready0[slot], s, __ATOMIC_RELEASE, __HIP_MEMORY_SCOPE_WORKGROUP);
        else
          __hip_atomic_store(&ready1[slot], s, __ATOMIC_RELEASE, __HIP_MEMORY_SCOPE_WORKGROUP);
      }
      int sn = s + 2;
      if (sn < NTIL) {                        // refill pipeline depth-2
        int pr = (w + sn * 32) * 32 + pair;
        int j = idxB[pr] & (NPTS - 1);
        unsigned n = (unsigned)pr / 20u;
#pragma unroll
        for (int k = 0; k < 4; ++k) {
          P[d][k] = *(const uint4*)(pB + (size_t)j * 128 + quarter * 32 + k * 8);
          Q[d][k] = *(const uint4*)(qB + (size_t)n * 128 + quarter * 32 + k * 8);
        }
      }
    }
  } else {
    // ---- CONSUMER (wave cg owns channels [cg*64, cg*64+64)) ----
    int cg = wid - 2;
    int col = lane & 31, hi = lane >> 5;
    v8h bfr0[8], bfr1[8];
#pragma unroll
    for (int kk = 0; kk < 8; ++kk) {
      const float* s0 = W3 + (size_t)(cg * 64 + col) * 128 + kk * 16 + hi * 8;
      const float* s1 = s0 + 32 * 128;
      v8h f0, f1;
#pragma unroll
      for (int jj = 0; jj < 8; ++jj) { f0[jj] = (_Float16)s0[jj]; f1[jj] = (_Float16)s1[jj]; }
      bfr0[kk] = f0; bfr1[kk] = f1;
    }

    float vmx0 = 0.f, vmx1 = 0.f;
    for (int s = 0; s < NTIL; ++s) {
      int slot = s - (s / RING) * RING;
      while (__hip_atomic_load(&ready0[slot], __ATOMIC_ACQUIRE,
                               __HIP_MEMORY_SCOPE_WORKGROUP) < s ||
             __hip_atomic_load(&ready1[slot], __ATOMIC_ACQUIRE,
                               __HIP_MEMORY_SCOPE_WORKGROUP) < s)
        __builtin_amdgcn_s_sleep(2);

      v16f acc0 = {0.f}, acc1 = {0.f};
#pragma unroll
      for (int kk = 0; kk < 8; ++kk) {
        v8h a = *(const v8h*)&tile[slot][col * 128 + (((kk * 2 + hi) ^ (col & 7)) * 8)];
        acc0 = __builtin_amdgcn_mfma_f32_32x32x16_f16(a, bfr0[kk], acc0, 0, 0, 0);
        acc1 = __builtin_amdgcn_mfma_f32_32x32x16_f16(a, bfr1[kk], acc1, 0, 0, 0);
      }
      if (lane == 0)                          // release: waits this wave's ds_reads
        __hip_atomic_fetch_add(&used[slot], 1, __ATOMIC_RELEASE, __HIP_MEMORY_SCOPE_WORKGROUP);

      float m0 = fmax3(acc0[0], acc0[1], acc0[2]);
      float m1 = fmax3(acc0[3], acc0[4], acc0[5]);
      float m2 = fmax3(acc0[6], acc0[7], acc0[8]);
      float m3 = fmax3(acc0[9], acc0[10], acc0[11]);
      float m4 = fmax3(acc0[12], acc0[13], acc0[14]);
      vmx0 = fmax3(fmax3(m0, m1, m2), fmax3(m3, m4, acc0[15]), vmx0);
      float n0 = fmax3(acc1[0], acc1[1], acc1[2]);
      float n1 = fmax3(acc1[3], acc1[4], acc1[5]);
      float n2 = fmax3(acc1[6], acc1[7], acc1[8]);
      float n3 = fmax3(acc1[9], acc1[10], acc1[11]);
      float n4 = fmax3(acc1[12], acc1[13], acc1[14]);
      vmx1 = fmax3(fmax3(n0, n1, n2), fmax3(n3, n4, acc1[15]), vmx1);
    }

    // lanes l and l^32 hold the same channel: reduce, write
    float v0 = fmaxf(vmx0, __shfl_xor(vmx0, 32));
    float v1 = fmaxf(vmx1, __shfl_xor(vmx1, 32));
    if (hi == 0) {
      atomicMax(&H[b * 256 + cg * 64 + col], __float_as_int(v0));
      atomicMax(&H[b * 256 + cg * 64 + 32 + col], __float_as_int(v1));
    }
  }
#undef RING
#undef NTIL
}

// ---------- K3: out = H @ fc_w^T + fc_b (one wave per output element) ----------
__global__ __launch_bounds__(64) void fc_kernel(const int* __restrict__ Hi,
                                                const float* __restrict__ fcw,
                                                const float* __restrict__ fcb,
                                                float* __restrict__ out) {
  int b = blockIdx.x / 10, r = blockIdx.x % 10;
  int lane = threadIdx.x;
  const float* Hb = (const float*)Hi + b * 256;
  float s = 0.f;
#pragma unroll
  for (int c = lane; c < 256; c += 64) s += Hb[c] * fcw[r * 256 + c];
#pragma unroll
  for (int m = 32; m > 0; m >>= 1) s += __shfl_xor(s, m);
  if (lane == 0) out[b * 10 + r] = s + fcb[r];
}

// ---------- launch ----------
extern "C" void kernel_launch(void* const* d_in, const int* in_sizes, int n_in,
                              void* d_out, int out_size, void* d_ws, size_t ws_size,
                              hipStream_t stream) {
  const float* x   = (const float*)d_in[0];
  const float* W1  = (const float*)d_in[1];
  const float* W2  = (const float*)d_in[2];
  const float* W3  = (const float*)d_in[3];
  const float* fcw = (const float*)d_in[4];
  const float* fcb = (const float*)d_in[5];
  float* out = (float*)d_out;
  char* ws = (char*)d_ws;

  // workspace layout (needs ~20 MB)
  int* H     = (int*)(ws + 4096);           // 16 KB (16x256 f32-as-int)
  int* idx   = (int*)(ws + 24576);          // 2.62 MB
  unsigned short* p = (unsigned short*)(ws + 3145728);   // 8.39 MB fp16
  unsigned short* q = (unsigned short*)(ws + 12582912);  // 8.39 MB fp16

  knn_kernel<<<BATCH * 32, 512, 0, stream>>>(x, idx, W1, W2, p, q, H);
  gemm_max_kernel<<<BATCH * 32, 384, 0, stream>>>(p, q, idx, W3, H);
  fc_kernel<<<BATCH * 10, 64, 0, stream>>>(H, fcw, fcb, out);
}

// Round 15
// 166.255 us; speedup vs baseline: 1.3611x; 1.3587x over previous
//
#include <hip/hip_runtime.h>
#include <stdint.h>

typedef _Float16 v8h __attribute__((ext_vector_type(8)));
typedef _Float16 v2h __attribute__((ext_vector_type(2)));
typedef float v4f __attribute__((ext_vector_type(4)));
typedef float v16f __attribute__((ext_vector_type(16)));

#define NPTS 2048
#define BATCH 16
#define KNN 20
#define PAIRS (NPTS * KNN)   // 40960 per batch

// ---------- helpers ----------
__device__ __forceinline__ unsigned pair_relu_h2(unsigned pu, unsigned qu) {
  v2h a = *(const v2h*)&pu;
  v2h b = *(const v2h*)&qu;
  v2h s = a + b;                                   // v_pk_add_f16
  v2h z = {(_Float16)0.f, (_Float16)0.f};
  v2h r = __builtin_elementwise_max(s, z);         // v_pk_max_f16 (relu)
  return *(const unsigned*)&r;
}
__device__ __forceinline__ float fmax3(float a, float b, float c) {
  return fmaxf(fmaxf(a, b), c);                    // fuses to v_max3_f32
}

// ---------- K1: fused exact-20NN + prep(M2, in LDS) + pq emission + H zero ----------
// R17: M2 computed once per block into LDS (R16's per-thread fold cost +18us).
// R10 knn core: norm-trick distances, 8 q/wave, 64-slot rank-count select.
__global__ __launch_bounds__(512, 2) void knn_kernel(
    const float* __restrict__ x, int* __restrict__ idxOut,
    const float* __restrict__ W1, const float* __restrict__ W2,
    unsigned short* __restrict__ p, unsigned short* __restrict__ q,
    int* __restrict__ H) {
  __shared__ float4 pts[NPTS];                    // 32 KB (x,y,z,|.|^2)
  __shared__ unsigned long long cand[8][8][64];   // 32 KB, wave-private
  __shared__ float M2s[128][6];                   // 3 KB: [ch][a0..2 | b0..2]
  int b = blockIdx.x >> 5;
  int qblk = blockIdx.x & 31;
  const float* xb = x + b * 3 * NPTS;

  if (qblk == 0 && threadIdx.x < 256) H[b * 256 + threadIdx.x] = 0;

  for (int i = threadIdx.x; i < NPTS; i += 512) {
    float X = xb[i], Y = xb[NPTS + i], Z = xb[2 * NPTS + i];
    pts[i] = make_float4(X, Y, Z, X * X + Y * Y + Z * Z);
  }

  // M2 once per block: thread o (<128) computes channel o's 6 coefficients.
  if (threadIdx.x < 128) {
    int o = threadIdx.x;
    const float* w2 = W2 + o * 64;
    float a0 = 0, a1 = 0, a2 = 0, a3 = 0, a4 = 0, a5 = 0;
    for (int i = 0; i < 64; ++i) {
      const float* w1r = W1 + i * 6;
      float w = w2[i];
      a0 += w * w1r[0]; a1 += w * w1r[1]; a2 += w * w1r[2];
      a3 += w * (w1r[3] - w1r[0]); a4 += w * (w1r[4] - w1r[1]); a5 += w * (w1r[5] - w1r[2]);
    }
    M2s[o][0] = a0; M2s[o][1] = a1; M2s[o][2] = a2;
    M2s[o][3] = a3; M2s[o][4] = a4; M2s[o][5] = a5;
  }
  __syncthreads();

  int wid = threadIdx.x >> 6, lane = threadIdx.x & 63;
  int qbase = qblk * 64 + wid * 8;                // 8 queries per wave

  // pq fold: emit p/q rows for this wave's 8 queries (coalesced stores).
  {
    int o0 = lane * 2;
    float a0 = M2s[o0][0], a1 = M2s[o0][1], a2 = M2s[o0][2];
    float a3 = M2s[o0][3], a4 = M2s[o0][4], a5 = M2s[o0][5];
    float c0 = M2s[o0 + 1][0], c1 = M2s[o0 + 1][1], c2 = M2s[o0 + 1][2];
    float c3 = M2s[o0 + 1][3], c4 = M2s[o0 + 1][4], c5 = M2s[o0 + 1][5];
    unsigned* pw = (unsigned*)p;
    unsigned* qw = (unsigned*)q;
#pragma unroll
    for (int g = 0; g < 8; ++g) {
      int j = qbase + g;
      float4 qp = pts[j];                         // broadcast LDS read
      float p0 = a0 * qp.x + a1 * qp.y + a2 * qp.z;
      float p1 = c0 * qp.x + c1 * qp.y + c2 * qp.z;
      float q0 = a3 * qp.x + a4 * qp.y + a5 * qp.z;
      float q1 = c3 * qp.x + c4 * qp.y + c5 * qp.z;
      size_t base = ((size_t)(b * NPTS + j)) * 64 + lane;
      auto hp = __builtin_amdgcn_cvt_pkrtz(p0, p1);
      auto hq = __builtin_amdgcn_cvt_pkrtz(q0, q1);
      pw[base] = *(const unsigned*)&hp;
      qw[base] = *(const unsigned*)&hq;
    }
  }

  float m2x[8], m2y[8], m2z[8], mn[8];
#pragma unroll
  for (int g = 0; g < 8; ++g) {
    float4 qp = pts[qbase + g];                   // broadcast read
    m2x[g] = -2.f * qp.x; m2y[g] = -2.f * qp.y; m2z[g] = -2.f * qp.z;
    mn[g] = 1e30f;
  }

  // pass 1: per-lane min over its 32 points, all 8 queries share the load
  for (int s = 0; s < 32; ++s) {
    float4 P = pts[s * 64 + lane];
#pragma unroll
    for (int g = 0; g < 8; ++g) {
      float d = fmaf(m2x[g], P.x, fmaf(m2y[g], P.y, fmaf(m2z[g], P.z, P.w)));
      mn[g] = fminf(mn[g], d);
    }
  }

  // tau[g] = 20th-smallest lane-min (upper bound on d'_(20)), inflated
  float tau[8];
#pragma unroll
  for (int g = 0; g < 8; ++g) {
    float v = mn[g];
    for (int k = 2; k <= 64; k <<= 1) {
      for (int j = k >> 1; j > 0; j >>= 1) {
        float o = __shfl_xor(v, j);
        bool low = (lane & j) == 0;
        bool up = (lane & k) == 0;
        v = (low == up) ? fminf(v, o) : fmaxf(v, o);
      }
    }
    float t = __shfl(v, 19);
    tau[g] = t + fabsf(t) * 4e-6f + 1e-6f;
  }

  // pass 2: recompute, ballot-compact candidates per query
  int cnt[8] = {0, 0, 0, 0, 0, 0, 0, 0};
  for (int s = 0; s < 32; ++s) {
    int i = s * 64 + lane;
    float4 P = pts[i];
#pragma unroll
    for (int g = 0; g < 8; ++g) {
      float d = fmaf(m2x[g], P.x, fmaf(m2y[g], P.y, fmaf(m2z[g], P.z, P.w)));
      bool take = d <= tau[g];
      unsigned long long mb = __ballot(take);
      if (take) {
        int pos = cnt[g] + __popcll(mb & ((1ull << lane) - 1ull));
        if (pos < 64) {
          unsigned kd = __float_as_uint(d + 64.f);   // d > -64: monotone key
          cand[wid][g][pos] = (((unsigned long long)kd) << 32) | (unsigned)i;
        }
      }
      cnt[g] += __popcll(mb);
    }
  }
  // cand written & read by the same wave: no __syncthreads needed.

  // rank-count select: broadcast reads; keys unique (index tiebreak).
#pragma unroll
  for (int g = 0; g < 8; ++g) {
    int nc = cnt[g] < 64 ? cnt[g] : 64;
    unsigned long long k0 = (lane < nc) ? cand[wid][g][lane] : ~0ull;
    int r0 = 0;
    for (int i = 0; i < nc; ++i) r0 += (cand[wid][g][i] < k0) ? 1 : 0;
    long long obase = ((long long)b * NPTS + qbase + g) * KNN;
    if (lane < nc && r0 < KNN) idxOut[obase + r0] = (int)(k0 & 0xffffffffu);
  }
}

// ---------- K2: h3 = relu(W3 · relu(p_j+q_n)), producer-consumer waves ----------
// R20: root cause of R18/R19's 122us found — rule #20: producer pipeline
// `uint4 P[2][4]` indexed by runtime d=s&1 -> arrays allocated in SCRATCH
// (explains VGPR=72, WRITE 26-33MB scratch write-back, launch_bounds no-op,
// MfmaUtil 14%). Fix: STATIC indexing — named PA/QA/PB/QB[4], two tiles per
// loop iteration (even->PA, odd->PB), all subscripts unroll-constant;
// slot/epoch tracked incrementally (no runtime div). Protocol unchanged
// (verified correct twice): waves 0-1 produce (gather, pair-relu, swizzled
// ds_write, 6-slot ring), waves 2-5 consume (poll -> ds_read_b128 -> 16
// MFMA -> max3). Monotonic flags, no __syncthreads in loop.
// PRE-COMMITTED TRIPWIRE: VGPR<=80 or WRITE>>1MB or dur>=51us -> revert to
// R14 gemm permanently next round.
__global__ __launch_bounds__(384, 2) void gemm_max_kernel(
    const unsigned short* __restrict__ p, const unsigned short* __restrict__ q,
    const int* __restrict__ idx, const float* __restrict__ W3, int* __restrict__ H) {
#define RING 6
#define NTIL 40                               // 1280 tiles / 32 blocks-per-batch
  __shared__ __align__(16) unsigned short tile[RING][32 * 128];  // 48 KB
  __shared__ int ready0[RING], ready1[RING], used[RING];

  int b = blockIdx.x & 15;
  int w = blockIdx.x >> 4;                    // 0..31
  int t = threadIdx.x;                        // 0..383
  int wid = t >> 6, lane = t & 63;

  if (t < RING) { ready0[t] = -1; ready1[t] = -1; used[t] = 0; }
  __syncthreads();                            // once, before role divergence

  const unsigned short* pB = p + (size_t)b * NPTS * 128;
  const unsigned short* qB = q + (size_t)b * NPTS * 128;
  const int* idxB = idx + (size_t)b * PAIRS;

  if (wid < 2) {
    // ---- PRODUCER (2 waves jointly stage each tile) ----
    int plane = wid * 64 + lane;              // 0..127
    int pair = plane >> 2;                    // 0..31
    int quarter = plane & 3;                  // 64B of p-row + 64B of q-row
    // swizzled store offsets (shorts): unit u = quarter*4+k -> u ^ (pair&7)
    int stoff[4];
#pragma unroll
    for (int k = 0; k < 4; ++k)
      stoff[k] = pair * 128 + (((quarter * 4 + k) ^ (pair & 7)) * 8);

    // 2-deep pipeline, STATIC register buffers (rule #20: no runtime index)
    uint4 PA[4], QA[4], PB_[4], QB_[4];
    {
      int pr = w * 32 + pair;                 // tile 0
      int j = idxB[pr] & (NPTS - 1);
      unsigned n = (unsigned)pr / 20u;
#pragma unroll
      for (int k = 0; k < 4; ++k) {
        PA[k] = *(const uint4*)(pB + (size_t)j * 128 + quarter * 32 + k * 8);
        QA[k] = *(const uint4*)(qB + (size_t)n * 128 + quarter * 32 + k * 8);
      }
      pr = (w + 32) * 32 + pair;              // tile 1
      j = idxB[pr] & (NPTS - 1);
      n = (unsigned)pr / 20u;
#pragma unroll
      for (int k = 0; k < 4; ++k) {
        PB_[k] = *(const uint4*)(pB + (size_t)j * 128 + quarter * 32 + k * 8);
        QB_[k] = *(const uint4*)(qB + (size_t)n * 128 + quarter * 32 + k * 8);
      }
    }

#define PRODUCE(S, PP, QQ)                                                   \
    {                                                                        \
      if (ep > 0) {                                                          \
        while (__hip_atomic_load(&used[slot], __ATOMIC_ACQUIRE,              \
                                 __HIP_MEMORY_SCOPE_WORKGROUP) < 4 * ep)     \
          __builtin_amdgcn_s_sleep(2);                                       \
      }                                                                      \
      _Pragma("unroll")                                                      \
      for (int k = 0; k < 4; ++k) {                                          \
        uint4 R;                                                             \
        R.x = pair_relu_h2(PP[k].x, QQ[k].x);                                \
        R.y = pair_relu_h2(PP[k].y, QQ[k].y);                                \
        R.z = pair_relu_h2(PP[k].z, QQ[k].z);                                \
        R.w = pair_relu_h2(PP[k].w, QQ[k].w);                                \
        *(uint4*)&tile[slot][stoff[k]] = R;                                  \
      }                                                                      \
      if (lane == 0) {                                                       \
        if (wid == 0)                                                        \
          __hip_atomic_store(&ready0[slot], (S), __ATOMIC_RELEASE,           \
                             __HIP_MEMORY_SCOPE_WORKGROUP);                  \
        else                                                                 \
          __hip_atomic_store(&ready1[slot], (S), __ATOMIC_RELEASE,           \
                             __HIP_MEMORY_SCOPE_WORKGROUP);                  \
      }                                                                      \
      int sn = (S) + 2;                                                      \
      if (sn < NTIL) {                                                       \
        int pr = (w + sn * 32) * 32 + pair;                                  \
        int j = idxB[pr] & (NPTS - 1);                                       \
        unsigned n = (unsigned)pr / 20u;                                     \
        _Pragma("unroll")                                                    \
        for (int k = 0; k < 4; ++k) {                                        \
          PP[k] = *(const uint4*)(pB + (size_t)j * 128 + quarter * 32 + k * 8); \
          QQ[k] = *(const uint4*)(qB + (size_t)n * 128 + quarter * 32 + k * 8); \
        }                                                                    \
      }                                                                      \
      if (++slot == RING) { slot = 0; ++ep; }                                \
    }

    int slot = 0, ep = 0;
    for (int s2 = 0; s2 < NTIL; s2 += 2) {
      PRODUCE(s2, PA, QA);
      PRODUCE(s2 + 1, PB_, QB_);
    }
#undef PRODUCE
  } else {
    // ---- CONSUMER (wave cg owns channels [cg*64, cg*64+64)) ----
    int cg = wid - 2;
    int col = lane & 31, hi = lane >> 5;
    v8h bfr0[8], bfr1[8];
#pragma unroll
    for (int kk = 0; kk < 8; ++kk) {
      const float* s0 = W3 + (size_t)(cg * 64 + col) * 128 + kk * 16 + hi * 8;
      const float* s1 = s0 + 32 * 128;
      v8h f0, f1;
#pragma unroll
      for (int jj = 0; jj < 8; ++jj) { f0[jj] = (_Float16)s0[jj]; f1[jj] = (_Float16)s1[jj]; }
      bfr0[kk] = f0; bfr1[kk] = f1;
    }

    float vmx0 = 0.f, vmx1 = 0.f;
    int slot = 0;
    for (int s = 0; s < NTIL; ++s) {
      while (__hip_atomic_load(&ready0[slot], __ATOMIC_ACQUIRE,
                               __HIP_MEMORY_SCOPE_WORKGROUP) < s ||
             __hip_atomic_load(&ready1[slot], __ATOMIC_ACQUIRE,
                               __HIP_MEMORY_SCOPE_WORKGROUP) < s)
        __builtin_amdgcn_s_sleep(2);

      v16f acc0 = {0.f}, acc1 = {0.f};
#pragma unroll
      for (int kk = 0; kk < 8; ++kk) {
        v8h a = *(const v8h*)&tile[slot][col * 128 + (((kk * 2 + hi) ^ (col & 7)) * 8)];
        acc0 = __builtin_amdgcn_mfma_f32_32x32x16_f16(a, bfr0[kk], acc0, 0, 0, 0);
        acc1 = __builtin_amdgcn_mfma_f32_32x32x16_f16(a, bfr1[kk], acc1, 0, 0, 0);
      }
      if (lane == 0)                          // release: waits this wave's ds_reads
        __hip_atomic_fetch_add(&used[slot], 1, __ATOMIC_RELEASE, __HIP_MEMORY_SCOPE_WORKGROUP);

      float m0 = fmax3(acc0[0], acc0[1], acc0[2]);
      float m1 = fmax3(acc0[3], acc0[4], acc0[5]);
      float m2 = fmax3(acc0[6], acc0[7], acc0[8]);
      float m3 = fmax3(acc0[9], acc0[10], acc0[11]);
      float m4 = fmax3(acc0[12], acc0[13], acc0[14]);
      vmx0 = fmax3(fmax3(m0, m1, m2), fmax3(m3, m4, acc0[15]), vmx0);
      float n0 = fmax3(acc1[0], acc1[1], acc1[2]);
      float n1 = fmax3(acc1[3], acc1[4], acc1[5]);
      float n2 = fmax3(acc1[6], acc1[7], acc1[8]);
      float n3 = fmax3(acc1[9], acc1[10], acc1[11]);
      float n4 = fmax3(acc1[12], acc1[13], acc1[14]);
      vmx1 = fmax3(fmax3(n0, n1, n2), fmax3(n3, n4, acc1[15]), vmx1);
      if (++slot == RING) slot = 0;
    }

    // lanes l and l^32 hold the same channel: reduce, write
    float v0 = fmaxf(vmx0, __shfl_xor(vmx0, 32));
    float v1 = fmaxf(vmx1, __shfl_xor(vmx1, 32));
    if (hi == 0) {
      atomicMax(&H[b * 256 + cg * 64 + col], __float_as_int(v0));
      atomicMax(&H[b * 256 + cg * 64 + 32 + col], __float_as_int(v1));
    }
  }
#undef RING
#undef NTIL
}

// ---------- K3: out = H @ fc_w^T + fc_b (one wave per output element) ----------
__global__ __launch_bounds__(64) void fc_kernel(const int* __restrict__ Hi,
                                                const float* __restrict__ fcw,
                                                const float* __restrict__ fcb,
                                                float* __restrict__ out) {
  int b = blockIdx.x / 10, r = blockIdx.x % 10;
  int lane = threadIdx.x;
  const float* Hb = (const float*)Hi + b * 256;
  float s = 0.f;
#pragma unroll
  for (int c = lane; c < 256; c += 64) s += Hb[c] * fcw[r * 256 + c];
#pragma unroll
  for (int m = 32; m > 0; m >>= 1) s += __shfl_xor(s, m);
  if (lane == 0) out[b * 10 + r] = s + fcb[r];
}

// ---------- launch ----------
extern "C" void kernel_launch(void* const* d_in, const int* in_sizes, int n_in,
                              void* d_out, int out_size, void* d_ws, size_t ws_size,
                              hipStream_t stream) {
  const float* x   = (const float*)d_in[0];
  const float* W1  = (const float*)d_in[1];
  const float* W2  = (const float*)d_in[2];
  const float* W3  = (const float*)d_in[3];
  const float* fcw = (const float*)d_in[4];
  const float* fcb = (const float*)d_in[5];
  float* out = (float*)d_out;
  char* ws = (char*)d_ws;

  // workspace layout (needs ~20 MB)
  int* H     = (int*)(ws + 4096);           // 16 KB (16x256 f32-as-int)
  int* idx   = (int*)(ws + 24576);          // 2.62 MB
  unsigned short* p = (unsigned short*)(ws + 3145728);   // 8.39 MB fp16
  unsigned short* q = (unsigned short*)(ws + 12582912);  // 8.39 MB fp16

  knn_kernel<<<BATCH * 32, 512, 0, stream>>>(x, idx, W1, W2, p, q, H);
  gemm_max_kernel<<<BATCH * 32, 384, 0, stream>>>(p, q, idx, W3, H);
  fc_kernel<<<BATCH * 10, 64, 0, stream>>>(H, fcw, fcb, out);
}

// Round 16
// 162.921 us; speedup vs baseline: 1.3889x; 1.0205x over previous
//
#include <hip/hip_runtime.h>
#include <stdint.h>

typedef _Float16 v8h __attribute__((ext_vector_type(8)));
typedef _Float16 v2h __attribute__((ext_vector_type(2)));
typedef float v4f __attribute__((ext_vector_type(4)));
typedef float v16f __attribute__((ext_vector_type(16)));

#define NPTS 2048
#define BATCH 16
#define KNN 20
#define PAIRS (NPTS * KNN)   // 40960 per batch

// ---------- helpers ----------
__device__ __forceinline__ unsigned pair_relu_h2(unsigned pu, unsigned qu) {
  v2h a = *(const v2h*)&pu;
  v2h b = *(const v2h*)&qu;
  v2h s = a + b;                                   // v_pk_add_f16
  v2h z = {(_Float16)0.f, (_Float16)0.f};
  v2h r = __builtin_elementwise_max(s, z);         // v_pk_max_f16 (relu)
  return *(const unsigned*)&r;
}
__device__ __forceinline__ float fmax3(float a, float b, float c) {
  return fmaxf(fmaxf(a, b), c);                    // fuses to v_max3_f32
}

// ---------- K1: fused exact-20NN + prep(M2, in LDS) + pq emission + H zero ----------
// R17: M2 computed once per block into LDS (R16's per-thread fold cost +18us).
// R21: tau via integer binary search on the monotone key float_as_uint(d+64)
// instead of the 84-stage bitonic: ~340 VALU inst/query -> ~35 VALU + ~120
// SALU (scalar pipe, free). Selection EXACT (smallest K with count>=20 =
// 20th order statistic); pass2 compares in key space, +48 key-ulps covers
// cross-pass FMA jitter (R3 lesson; ~4e-6 relative, same as old margin).
// R10 knn core kept: norm-trick distances, 8 q/wave, 64-slot rank-count.
__global__ __launch_bounds__(512, 2) void knn_kernel(
    const float* __restrict__ x, int* __restrict__ idxOut,
    const float* __restrict__ W1, const float* __restrict__ W2,
    unsigned short* __restrict__ p, unsigned short* __restrict__ q,
    int* __restrict__ H) {
  __shared__ float4 pts[NPTS];                    // 32 KB (x,y,z,|.|^2)
  __shared__ unsigned long long cand[8][8][64];   // 32 KB, wave-private
  __shared__ float M2s[128][6];                   // 3 KB: [ch][a0..2 | b0..2]
  int b = blockIdx.x >> 5;
  int qblk = blockIdx.x & 31;
  const float* xb = x + b * 3 * NPTS;

  if (qblk == 0 && threadIdx.x < 256) H[b * 256 + threadIdx.x] = 0;

  for (int i = threadIdx.x; i < NPTS; i += 512) {
    float X = xb[i], Y = xb[NPTS + i], Z = xb[2 * NPTS + i];
    pts[i] = make_float4(X, Y, Z, X * X + Y * Y + Z * Z);
  }

  // M2 once per block: thread o (<128) computes channel o's 6 coefficients.
  if (threadIdx.x < 128) {
    int o = threadIdx.x;
    const float* w2 = W2 + o * 64;
    float a0 = 0, a1 = 0, a2 = 0, a3 = 0, a4 = 0, a5 = 0;
    for (int i = 0; i < 64; ++i) {
      const float* w1r = W1 + i * 6;
      float w = w2[i];
      a0 += w * w1r[0]; a1 += w * w1r[1]; a2 += w * w1r[2];
      a3 += w * (w1r[3] - w1r[0]); a4 += w * (w1r[4] - w1r[1]); a5 += w * (w1r[5] - w1r[2]);
    }
    M2s[o][0] = a0; M2s[o][1] = a1; M2s[o][2] = a2;
    M2s[o][3] = a3; M2s[o][4] = a4; M2s[o][5] = a5;
  }
  __syncthreads();

  int wid = threadIdx.x >> 6, lane = threadIdx.x & 63;
  int qbase = qblk * 64 + wid * 8;                // 8 queries per wave

  // pq fold: emit p/q rows for this wave's 8 queries (coalesced stores).
  {
    int o0 = lane * 2;
    float a0 = M2s[o0][0], a1 = M2s[o0][1], a2 = M2s[o0][2];
    float a3 = M2s[o0][3], a4 = M2s[o0][4], a5 = M2s[o0][5];
    float c0 = M2s[o0 + 1][0], c1 = M2s[o0 + 1][1], c2 = M2s[o0 + 1][2];
    float c3 = M2s[o0 + 1][3], c4 = M2s[o0 + 1][4], c5 = M2s[o0 + 1][5];
    unsigned* pw = (unsigned*)p;
    unsigned* qw = (unsigned*)q;
#pragma unroll
    for (int g = 0; g < 8; ++g) {
      int j = qbase + g;
      float4 qp = pts[j];                         // broadcast LDS read
      float p0 = a0 * qp.x + a1 * qp.y + a2 * qp.z;
      float p1 = c0 * qp.x + c1 * qp.y + c2 * qp.z;
      float q0 = a3 * qp.x + a4 * qp.y + a5 * qp.z;
      float q1 = c3 * qp.x + c4 * qp.y + c5 * qp.z;
      size_t base = ((size_t)(b * NPTS + j)) * 64 + lane;
      auto hp = __builtin_amdgcn_cvt_pkrtz(p0, p1);
      auto hq = __builtin_amdgcn_cvt_pkrtz(q0, q1);
      pw[base] = *(const unsigned*)&hp;
      qw[base] = *(const unsigned*)&hq;
    }
  }

  float m2x[8], m2y[8], m2z[8], mn[8];
#pragma unroll
  for (int g = 0; g < 8; ++g) {
    float4 qp = pts[qbase + g];                   // broadcast read
    m2x[g] = -2.f * qp.x; m2y[g] = -2.f * qp.y; m2z[g] = -2.f * qp.z;
    mn[g] = 1e30f;
  }

  // pass 1: per-lane min over its 32 points, all 8 queries share the load
  for (int s = 0; s < 32; ++s) {
    float4 P = pts[s * 64 + lane];
#pragma unroll
    for (int g = 0; g < 8; ++g) {
      float d = fmaf(m2x[g], P.x, fmaf(m2y[g], P.y, fmaf(m2z[g], P.z, P.w)));
      mn[g] = fminf(mn[g], d);
    }
  }

  // tau key = 20th-smallest lane-min key (exact, binary search in key space)
  // key = float_as_uint(d + 64): d > -64 always here -> positive floats,
  // uint order == float order. lo/hi wave-uniform (SALU); 31 iters converge.
  unsigned tauK[8];
#pragma unroll
  for (int g = 0; g < 8; ++g) {
    unsigned key = __float_as_uint(mn[g] + 64.f);
    unsigned lo = 0u, hi = 0x7F000000u;
    for (int it = 0; it < 31; ++it) {
      unsigned mid = (lo + hi) >> 1;
      int c = __popcll(__ballot(key <= mid));
      if (c >= KNN) hi = mid; else lo = mid + 1;
    }
    tauK[g] = hi + 48u;   // +48 key-ulps: covers cross-pass FMA jitter
  }

  // pass 2: recompute, ballot-compact candidates per query (key-space cmp)
  int cnt[8] = {0, 0, 0, 0, 0, 0, 0, 0};
  for (int s = 0; s < 32; ++s) {
    int i = s * 64 + lane;
    float4 P = pts[i];
#pragma unroll
    for (int g = 0; g < 8; ++g) {
      float d = fmaf(m2x[g], P.x, fmaf(m2y[g], P.y, fmaf(m2z[g], P.z, P.w)));
      unsigned kd = __float_as_uint(d + 64.f);
      bool take = kd <= tauK[g];
      unsigned long long mb = __ballot(take);
      if (take) {
        int pos = cnt[g] + __popcll(mb & ((1ull << lane) - 1ull));
        if (pos < 64)
          cand[wid][g][pos] = (((unsigned long long)kd) << 32) | (unsigned)i;
      }
      cnt[g] += __popcll(mb);
    }
  }
  // cand written & read by the same wave: no __syncthreads needed.

  // rank-count select: broadcast reads; keys unique (index tiebreak).
#pragma unroll
  for (int g = 0; g < 8; ++g) {
    int nc = cnt[g] < 64 ? cnt[g] : 64;
    unsigned long long k0 = (lane < nc) ? cand[wid][g][lane] : ~0ull;
    int r0 = 0;
    for (int i = 0; i < nc; ++i) r0 += (cand[wid][g][i] < k0) ? 1 : 0;
    long long obase = ((long long)b * NPTS + qbase + g) * KNN;
    if (lane < nc && r0 < KNN) idxOut[obase + r0] = (int)(k0 & 0xffffffffu);
  }
}

// ---------- K2: h3 = relu(W3 · relu(p_j+q_n)) via MFMA, fused max-reduce ----------
// R21: REVERTED to R14 (measured 51.0us, MfmaUtil 33%) per the R20
// pre-commitment. Producer-consumer specialization refuted with clean
// counters (R20: 64us, MfmaUtil 27% — producer waves + polling cost more
// than decorrelation wins at this tile size). R14 = the local optimum:
// TWO tiles per barrier, 4-buffer LDS (2 dbuf x 2 tiles = 32KB), 10 exact
// iters, batch->XCD pin, idx prefetch 2 iters ahead, swizzled LDS.
// R11 lesson: launch_bounds (256,3), never (256,4) (VGPR cap -> spill).
__global__ __launch_bounds__(256, 3) void gemm_max_kernel(
    const unsigned short* __restrict__ p, const unsigned short* __restrict__ q,
    const int* __restrict__ idx, const float* __restrict__ W3, int* __restrict__ H) {
  __shared__ __align__(16) unsigned short h2s[2][2][32 * 128];  // 32 KB: dbuf x 2 tiles

  int b = blockIdx.x & 15;
  int w = blockIdx.x >> 4;            // 0..63
  int t = threadIdx.x;                // 0..255
  int lane = t & 63, wid = t >> 6;    // 4 waves
  int col = lane & 31, hi = lane >> 5;

  // B fragments: wave owns channels [wid*64, wid*64+64) as 2 ntiles.
  v8h bfr0[8], bfr1[8];
#pragma unroll
  for (int kk = 0; kk < 8; ++kk) {
    const float* s0 = W3 + (size_t)(wid * 64 + col) * 128 + kk * 16 + hi * 8;
    const float* s1 = s0 + 32 * 128;
    v8h f0, f1;
#pragma unroll
    for (int jj = 0; jj < 8; ++jj) { f0[jj] = (_Float16)s0[jj]; f1[jj] = (_Float16)s1[jj]; }
    bfr0[kk] = f0; bfr1[kk] = f1;
  }

  const unsigned short* pB = p + (size_t)b * NPTS * 128;
  const unsigned short* qB = q + (size_t)b * NPTS * 128;
  const int* idxB = idx + (size_t)b * PAIRS;

  int pm = t >> 3;        // pair-in-tile 0..31
  int c2 = t & 7;         // covers 16B units 2*c2, 2*c2+1 (32B of the row)
  int st0 = pm * 128 + (((c2 * 2) ^ (pm & 7)) * 8);
  int st1 = pm * 128 + (((c2 * 2 + 1) ^ (pm & 7)) * 8);

  const int NT = PAIRS / 32;          // 1280 tiles; iter = {T, T+64}, T += 128

  uint4 PA0, PA1, QA0, QA1, PB0, PB1, QB0, QB1;
  int jnA, jnB;
  {
    int prA = w * 32 + pm, prB = (w + 64) * 32 + pm;
    int jA = idxB[prA] & (NPTS - 1);
    int jB = idxB[prB] & (NPTS - 1);
    int nA = prA / 20, nB = prB / 20;
    PA0 = *(const uint4*)(pB + (size_t)jA * 128 + c2 * 16);
    PA1 = *(const uint4*)(pB + (size_t)jA * 128 + c2 * 16 + 8);
    QA0 = *(const uint4*)(qB + (size_t)nA * 128 + c2 * 16);
    QA1 = *(const uint4*)(qB + (size_t)nA * 128 + c2 * 16 + 8);
    PB0 = *(const uint4*)(pB + (size_t)jB * 128 + c2 * 16);
    PB1 = *(const uint4*)(pB + (size_t)jB * 128 + c2 * 16 + 8);
    QB0 = *(const uint4*)(qB + (size_t)nB * 128 + c2 * 16);
    QB1 = *(const uint4*)(qB + (size_t)nB * 128 + c2 * 16 + 8);
    jnA = idxB[(w + 128) * 32 + pm];
    jnB = idxB[(w + 192) * 32 + pm];
  }

  float vmx0 = 0.f, vmx1 = 0.f;
  int buf = 0;
  for (int T = w; T < NT; T += 128) {   // 10 exact iterations
    uint4 R;
    R.x = pair_relu_h2(PA0.x, QA0.x); R.y = pair_relu_h2(PA0.y, QA0.y);
    R.z = pair_relu_h2(PA0.z, QA0.z); R.w = pair_relu_h2(PA0.w, QA0.w);
    *(uint4*)&h2s[buf][0][st0] = R;
    R.x = pair_relu_h2(PA1.x, QA1.x); R.y = pair_relu_h2(PA1.y, QA1.y);
    R.z = pair_relu_h2(PA1.z, QA1.z); R.w = pair_relu_h2(PA1.w, QA1.w);
    *(uint4*)&h2s[buf][0][st1] = R;
    R.x = pair_relu_h2(PB0.x, QB0.x); R.y = pair_relu_h2(PB0.y, QB0.y);
    R.z = pair_relu_h2(PB0.z, QB0.z); R.w = pair_relu_h2(PB0.w, QB0.w);
    *(uint4*)&h2s[buf][1][st0] = R;
    R.x = pair_relu_h2(PB1.x, QB1.x); R.y = pair_relu_h2(PB1.y, QB1.y);
    R.z = pair_relu_h2(PB1.z, QB1.z); R.w = pair_relu_h2(PB1.w, QB1.w);
    *(uint4*)&h2s[buf][1][st1] = R;
    __syncthreads();

    int Tn = T + 128;
    if (Tn < NT) {
      int prA = Tn * 32 + pm, prB = (Tn + 64) * 32 + pm;
      int jA = jnA & (NPTS - 1), jB = jnB & (NPTS - 1);
      int nA = prA / 20, nB = prB / 20;
      PA0 = *(const uint4*)(pB + (size_t)jA * 128 + c2 * 16);
      PA1 = *(const uint4*)(pB + (size_t)jA * 128 + c2 * 16 + 8);
      QA0 = *(const uint4*)(qB + (size_t)nA * 128 + c2 * 16);
      QA1 = *(const uint4*)(qB + (size_t)nA * 128 + c2 * 16 + 8);
      PB0 = *(const uint4*)(pB + (size_t)jB * 128 + c2 * 16);
      PB1 = *(const uint4*)(pB + (size_t)jB * 128 + c2 * 16 + 8);
      QB0 = *(const uint4*)(qB + (size_t)nB * 128 + c2 * 16);
      QB1 = *(const uint4*)(qB + (size_t)nB * 128 + c2 * 16 + 8);
      int T2 = T + 256;
      if (T2 < NT) {
        jnA = idxB[T2 * 32 + pm];
        jnB = idxB[(T2 + 64) * 32 + pm];
      }
    }

    {
      v16f acc0 = {0.f}, acc1 = {0.f};
#pragma unroll
      for (int kk = 0; kk < 8; ++kk) {
        v8h a = *(const v8h*)&h2s[buf][0][col * 128 + (((kk * 2 + hi) ^ (col & 7)) * 8)];
        acc0 = __builtin_amdgcn_mfma_f32_32x32x16_f16(a, bfr0[kk], acc0, 0, 0, 0);
        acc1 = __builtin_amdgcn_mfma_f32_32x32x16_f16(a, bfr1[kk], acc1, 0, 0, 0);
      }
      float m0 = fmax3(acc0[0], acc0[1], acc0[2]);
      float m1 = fmax3(acc0[3], acc0[4], acc0[5]);
      float m2 = fmax3(acc0[6], acc0[7], acc0[8]);
      float m3 = fmax3(acc0[9], acc0[10], acc0[11]);
      float m4 = fmax3(acc0[12], acc0[13], acc0[14]);
      vmx0 = fmax3(fmax3(m0, m1, m2), fmax3(m3, m4, acc0[15]), vmx0);
      float n0 = fmax3(acc1[0], acc1[1], acc1[2]);
      float n1 = fmax3(acc1[3], acc1[4], acc1[5]);
      float n2 = fmax3(acc1[6], acc1[7], acc1[8]);
      float n3 = fmax3(acc1[9], acc1[10], acc1[11]);
      float n4 = fmax3(acc1[12], acc1[13], acc1[14]);
      vmx1 = fmax3(fmax3(n0, n1, n2), fmax3(n3, n4, acc1[15]), vmx1);
    }
    {
      v16f acc0 = {0.f}, acc1 = {0.f};
#pragma unroll
      for (int kk = 0; kk < 8; ++kk) {
        v8h a = *(const v8h*)&h2s[buf][1][col * 128 + (((kk * 2 + hi) ^ (col & 7)) * 8)];
        acc0 = __builtin_amdgcn_mfma_f32_32x32x16_f16(a, bfr0[kk], acc0, 0, 0, 0);
        acc1 = __builtin_amdgcn_mfma_f32_32x32x16_f16(a, bfr1[kk], acc1, 0, 0, 0);
      }
      float m0 = fmax3(acc0[0], acc0[1], acc0[2]);
      float m1 = fmax3(acc0[3], acc0[4], acc0[5]);
      float m2 = fmax3(acc0[6], acc0[7], acc0[8]);
      float m3 = fmax3(acc0[9], acc0[10], acc0[11]);
      float m4 = fmax3(acc0[12], acc0[13], acc0[14]);
      vmx0 = fmax3(fmax3(m0, m1, m2), fmax3(m3, m4, acc0[15]), vmx0);
      float n0 = fmax3(acc1[0], acc1[1], acc1[2]);
      float n1 = fmax3(acc1[3], acc1[4], acc1[5]);
      float n2 = fmax3(acc1[6], acc1[7], acc1[8]);
      float n3 = fmax3(acc1[9], acc1[10], acc1[11]);
      float n4 = fmax3(acc1[12], acc1[13], acc1[14]);
      vmx1 = fmax3(fmax3(n0, n1, n2), fmax3(n3, n4, acc1[15]), vmx1);
    }
    buf ^= 1;
  }

  float v0 = fmaxf(vmx0, __shfl_xor(vmx0, 32));
  float v1 = fmaxf(vmx1, __shfl_xor(vmx1, 32));
  if (hi == 0) {
    atomicMax(&H[b * 256 + wid * 64 + col], __float_as_int(v0));
    atomicMax(&H[b * 256 + wid * 64 + 32 + col], __float_as_int(v1));
  }
}

// ---------- K3: out = H @ fc_w^T + fc_b (one wave per output element) ----------
__global__ __launch_bounds__(64) void fc_kernel(const int* __restrict__ Hi,
                                                const float* __restrict__ fcw,
                                                const float* __restrict__ fcb,
                                                float* __restrict__ out) {
  int b = blockIdx.x / 10, r = blockIdx.x % 10;
  int lane = threadIdx.x;
  const float* Hb = (const float*)Hi + b * 256;
  float s = 0.f;
#pragma unroll
  for (int c = lane; c < 256; c += 64) s += Hb[c] * fcw[r * 256 + c];
#pragma unroll
  for (int m = 32; m > 0; m >>= 1) s += __shfl_xor(s, m);
  if (lane == 0) out[b * 10 + r] = s + fcb[r];
}

// ---------- launch ----------
extern "C" void kernel_launch(void* const* d_in, const int* in_sizes, int n_in,
                              void* d_out, int out_size, void* d_ws, size_t ws_size,
                              hipStream_t stream) {
  const float* x   = (const float*)d_in[0];
  const float* W1  = (const float*)d_in[1];
  const float* W2  = (const float*)d_in[2];
  const float* W3  = (const float*)d_in[3];
  const float* fcw = (const float*)d_in[4];
  const float* fcb = (const float*)d_in[5];
  float* out = (float*)d_out;
  char* ws = (char*)d_ws;

  // workspace layout (needs ~20 MB)
  int* H     = (int*)(ws + 4096);           // 16 KB (16x256 f32-as-int)
  int* idx   = (int*)(ws + 24576);          // 2.62 MB
  unsigned short* p = (unsigned short*)(ws + 3145728);   // 8.39 MB fp16
  unsigned short* q = (unsigned short*)(ws + 12582912);  // 8.39 MB fp16

  knn_kernel<<<BATCH * 32, 512, 0, stream>>>(x, idx, W1, W2, p, q, H);
  gemm_max_kernel<<<BATCH * 64, 256, 0, stream>>>(p, q, idx, W3, H);
  fc_kernel<<<BATCH * 10, 64, 0, stream>>>(H, fcw, fcb, out);
}

// Round 17
// 158.036 us; speedup vs baseline: 1.4319x; 1.0309x over previous
//
#include <hip/hip_runtime.h>
#include <stdint.h>

typedef _Float16 v8h __attribute__((ext_vector_type(8)));
typedef _Float16 v2h __attribute__((ext_vector_type(2)));
typedef float v4f __attribute__((ext_vector_type(4)));
typedef float v16f __attribute__((ext_vector_type(16)));

#define NPTS 2048
#define BATCH 16
#define KNN 20
#define PAIRS (NPTS * KNN)   // 40960 per batch

// ---------- helpers ----------
__device__ __forceinline__ unsigned pair_relu_h2(unsigned pu, unsigned qu) {
  v2h a = *(const v2h*)&pu;
  v2h b = *(const v2h*)&qu;
  v2h s = a + b;                                   // v_pk_add_f16
  v2h z = {(_Float16)0.f, (_Float16)0.f};
  v2h r = __builtin_elementwise_max(s, z);         // v_pk_max_f16 (relu)
  return *(const unsigned*)&r;
}
__device__ __forceinline__ float fmax3(float a, float b, float c) {
  return fmaxf(fmaxf(a, b), c);                    // fuses to v_max3_f32
}

// ---------- K1: fused exact-20NN + prep(M2, in LDS) + pq emission + H zero ----------
// R22: REVERT to R17 exactly (measured session best, 158.1us total).
// R21's binary-search tau regressed knn 52->57us: 31 serially-dependent
// {v_cmp -> vcc->SALU -> select} steps x8 queries have no ILP; the bitonic's
// 84 stages run with full 8-query ILP (dependency DEPTH beats inst COUNT).
// R17: M2 once per block in LDS; pq emission fused; H zero fused.
// R10 knn core: norm-trick distances, 8 q/wave, 64-slot rank-count select.
__global__ __launch_bounds__(512, 2) void knn_kernel(
    const float* __restrict__ x, int* __restrict__ idxOut,
    const float* __restrict__ W1, const float* __restrict__ W2,
    unsigned short* __restrict__ p, unsigned short* __restrict__ q,
    int* __restrict__ H) {
  __shared__ float4 pts[NPTS];                    // 32 KB (x,y,z,|.|^2)
  __shared__ unsigned long long cand[8][8][64];   // 32 KB, wave-private
  __shared__ float M2s[128][6];                   // 3 KB: [ch][a0..2 | b0..2]
  int b = blockIdx.x >> 5;
  int qblk = blockIdx.x & 31;
  const float* xb = x + b * 3 * NPTS;

  if (qblk == 0 && threadIdx.x < 256) H[b * 256 + threadIdx.x] = 0;

  for (int i = threadIdx.x; i < NPTS; i += 512) {
    float X = xb[i], Y = xb[NPTS + i], Z = xb[2 * NPTS + i];
    pts[i] = make_float4(X, Y, Z, X * X + Y * Y + Z * Z);
  }

  // M2 once per block: thread o (<128) computes channel o's 6 coefficients.
  if (threadIdx.x < 128) {
    int o = threadIdx.x;
    const float* w2 = W2 + o * 64;
    float a0 = 0, a1 = 0, a2 = 0, a3 = 0, a4 = 0, a5 = 0;
    for (int i = 0; i < 64; ++i) {
      const float* w1r = W1 + i * 6;
      float w = w2[i];
      a0 += w * w1r[0]; a1 += w * w1r[1]; a2 += w * w1r[2];
      a3 += w * (w1r[3] - w1r[0]); a4 += w * (w1r[4] - w1r[1]); a5 += w * (w1r[5] - w1r[2]);
    }
    M2s[o][0] = a0; M2s[o][1] = a1; M2s[o][2] = a2;
    M2s[o][3] = a3; M2s[o][4] = a4; M2s[o][5] = a5;
  }
  __syncthreads();

  int wid = threadIdx.x >> 6, lane = threadIdx.x & 63;
  int qbase = qblk * 64 + wid * 8;                // 8 queries per wave

  // pq fold: emit p/q rows for this wave's 8 queries (coalesced stores).
  {
    int o0 = lane * 2;
    float a0 = M2s[o0][0], a1 = M2s[o0][1], a2 = M2s[o0][2];
    float a3 = M2s[o0][3], a4 = M2s[o0][4], a5 = M2s[o0][5];
    float c0 = M2s[o0 + 1][0], c1 = M2s[o0 + 1][1], c2 = M2s[o0 + 1][2];
    float c3 = M2s[o0 + 1][3], c4 = M2s[o0 + 1][4], c5 = M2s[o0 + 1][5];
    unsigned* pw = (unsigned*)p;
    unsigned* qw = (unsigned*)q;
#pragma unroll
    for (int g = 0; g < 8; ++g) {
      int j = qbase + g;
      float4 qp = pts[j];                         // broadcast LDS read
      float p0 = a0 * qp.x + a1 * qp.y + a2 * qp.z;
      float p1 = c0 * qp.x + c1 * qp.y + c2 * qp.z;
      float q0 = a3 * qp.x + a4 * qp.y + a5 * qp.z;
      float q1 = c3 * qp.x + c4 * qp.y + c5 * qp.z;
      size_t base = ((size_t)(b * NPTS + j)) * 64 + lane;
      auto hp = __builtin_amdgcn_cvt_pkrtz(p0, p1);
      auto hq = __builtin_amdgcn_cvt_pkrtz(q0, q1);
      pw[base] = *(const unsigned*)&hp;
      qw[base] = *(const unsigned*)&hq;
    }
  }

  float m2x[8], m2y[8], m2z[8], mn[8];
#pragma unroll
  for (int g = 0; g < 8; ++g) {
    float4 qp = pts[qbase + g];                   // broadcast read
    m2x[g] = -2.f * qp.x; m2y[g] = -2.f * qp.y; m2z[g] = -2.f * qp.z;
    mn[g] = 1e30f;
  }

  // pass 1: per-lane min over its 32 points, all 8 queries share the load
  for (int s = 0; s < 32; ++s) {
    float4 P = pts[s * 64 + lane];
#pragma unroll
    for (int g = 0; g < 8; ++g) {
      float d = fmaf(m2x[g], P.x, fmaf(m2y[g], P.y, fmaf(m2z[g], P.z, P.w)));
      mn[g] = fminf(mn[g], d);
    }
  }

  // tau[g] = 20th-smallest lane-min (upper bound on d'_(20)), inflated
  float tau[8];
#pragma unroll
  for (int g = 0; g < 8; ++g) {
    float v = mn[g];
    for (int k = 2; k <= 64; k <<= 1) {
      for (int j = k >> 1; j > 0; j >>= 1) {
        float o = __shfl_xor(v, j);
        bool low = (lane & j) == 0;
        bool up = (lane & k) == 0;
        v = (low == up) ? fminf(v, o) : fmaxf(v, o);
      }
    }
    float t = __shfl(v, 19);
    tau[g] = t + fabsf(t) * 4e-6f + 1e-6f;
  }

  // pass 2: recompute, ballot-compact candidates per query
  int cnt[8] = {0, 0, 0, 0, 0, 0, 0, 0};
  for (int s = 0; s < 32; ++s) {
    int i = s * 64 + lane;
    float4 P = pts[i];
#pragma unroll
    for (int g = 0; g < 8; ++g) {
      float d = fmaf(m2x[g], P.x, fmaf(m2y[g], P.y, fmaf(m2z[g], P.z, P.w)));
      bool take = d <= tau[g];
      unsigned long long mb = __ballot(take);
      if (take) {
        int pos = cnt[g] + __popcll(mb & ((1ull << lane) - 1ull));
        if (pos < 64) {
          unsigned kd = __float_as_uint(d + 64.f);   // d > -64: monotone key
          cand[wid][g][pos] = (((unsigned long long)kd) << 32) | (unsigned)i;
        }
      }
      cnt[g] += __popcll(mb);
    }
  }
  // cand written & read by the same wave: no __syncthreads needed.

  // rank-count select: broadcast reads; keys unique (index tiebreak).
#pragma unroll
  for (int g = 0; g < 8; ++g) {
    int nc = cnt[g] < 64 ? cnt[g] : 64;
    unsigned long long k0 = (lane < nc) ? cand[wid][g][lane] : ~0ull;
    int r0 = 0;
    for (int i = 0; i < nc; ++i) r0 += (cand[wid][g][i] < k0) ? 1 : 0;
    long long obase = ((long long)b * NPTS + qbase + g) * KNN;
    if (lane < nc && r0 < KNN) idxOut[obase + r0] = (int)(k0 & 0xffffffffu);
  }
}

// ---------- K2: h3 = relu(W3 · relu(p_j+q_n)) via MFMA, fused max-reduce ----------
// R14 structure (measured best: 51.0us, MfmaUtil 33% = its equilibrium):
// TWO tiles per barrier, 4-buffer LDS (2 dbuf x 2 tiles = 32KB), 10 exact
// iters, batch->XCD pin, idx prefetch 2 iters ahead, swizzled LDS.
// Refuted alternatives: barrier-free gather (R15, coalescing 2.3x loss),
// producer-consumer waves (R20, 27% MfmaUtil with clean counters).
// R11 lesson: launch_bounds (256,3), never (256,4) (VGPR cap -> spill).
__global__ __launch_bounds__(256, 3) void gemm_max_kernel(
    const unsigned short* __restrict__ p, const unsigned short* __restrict__ q,
    const int* __restrict__ idx, const float* __restrict__ W3, int* __restrict__ H) {
  __shared__ __align__(16) unsigned short h2s[2][2][32 * 128];  // 32 KB: dbuf x 2 tiles

  int b = blockIdx.x & 15;
  int w = blockIdx.x >> 4;            // 0..63
  int t = threadIdx.x;                // 0..255
  int lane = t & 63, wid = t >> 6;    // 4 waves
  int col = lane & 31, hi = lane >> 5;

  // B fragments: wave owns channels [wid*64, wid*64+64) as 2 ntiles.
  v8h bfr0[8], bfr1[8];
#pragma unroll
  for (int kk = 0; kk < 8; ++kk) {
    const float* s0 = W3 + (size_t)(wid * 64 + col) * 128 + kk * 16 + hi * 8;
    const float* s1 = s0 + 32 * 128;
    v8h f0, f1;
#pragma unroll
    for (int jj = 0; jj < 8; ++jj) { f0[jj] = (_Float16)s0[jj]; f1[jj] = (_Float16)s1[jj]; }
    bfr0[kk] = f0; bfr1[kk] = f1;
  }

  const unsigned short* pB = p + (size_t)b * NPTS * 128;
  const unsigned short* qB = q + (size_t)b * NPTS * 128;
  const int* idxB = idx + (size_t)b * PAIRS;

  int pm = t >> 3;        // pair-in-tile 0..31
  int c2 = t & 7;         // covers 16B units 2*c2, 2*c2+1 (32B of the row)
  int st0 = pm * 128 + (((c2 * 2) ^ (pm & 7)) * 8);
  int st1 = pm * 128 + (((c2 * 2 + 1) ^ (pm & 7)) * 8);

  const int NT = PAIRS / 32;          // 1280 tiles; iter = {T, T+64}, T += 128

  uint4 PA0, PA1, QA0, QA1, PB0, PB1, QB0, QB1;
  int jnA, jnB;
  {
    int prA = w * 32 + pm, prB = (w + 64) * 32 + pm;
    int jA = idxB[prA] & (NPTS - 1);
    int jB = idxB[prB] & (NPTS - 1);
    int nA = prA / 20, nB = prB / 20;
    PA0 = *(const uint4*)(pB + (size_t)jA * 128 + c2 * 16);
    PA1 = *(const uint4*)(pB + (size_t)jA * 128 + c2 * 16 + 8);
    QA0 = *(const uint4*)(qB + (size_t)nA * 128 + c2 * 16);
    QA1 = *(const uint4*)(qB + (size_t)nA * 128 + c2 * 16 + 8);
    PB0 = *(const uint4*)(pB + (size_t)jB * 128 + c2 * 16);
    PB1 = *(const uint4*)(pB + (size_t)jB * 128 + c2 * 16 + 8);
    QB0 = *(const uint4*)(qB + (size_t)nB * 128 + c2 * 16);
    QB1 = *(const uint4*)(qB + (size_t)nB * 128 + c2 * 16 + 8);
    jnA = idxB[(w + 128) * 32 + pm];
    jnB = idxB[(w + 192) * 32 + pm];
  }

  float vmx0 = 0.f, vmx1 = 0.f;
  int buf = 0;
  for (int T = w; T < NT; T += 128) {   // 10 exact iterations
    uint4 R;
    R.x = pair_relu_h2(PA0.x, QA0.x); R.y = pair_relu_h2(PA0.y, QA0.y);
    R.z = pair_relu_h2(PA0.z, QA0.z); R.w = pair_relu_h2(PA0.w, QA0.w);
    *(uint4*)&h2s[buf][0][st0] = R;
    R.x = pair_relu_h2(PA1.x, QA1.x); R.y = pair_relu_h2(PA1.y, QA1.y);
    R.z = pair_relu_h2(PA1.z, QA1.z); R.w = pair_relu_h2(PA1.w, QA1.w);
    *(uint4*)&h2s[buf][0][st1] = R;
    R.x = pair_relu_h2(PB0.x, QB0.x); R.y = pair_relu_h2(PB0.y, QB0.y);
    R.z = pair_relu_h2(PB0.z, QB0.z); R.w = pair_relu_h2(PB0.w, QB0.w);
    *(uint4*)&h2s[buf][1][st0] = R;
    R.x = pair_relu_h2(PB1.x, QB1.x); R.y = pair_relu_h2(PB1.y, QB1.y);
    R.z = pair_relu_h2(PB1.z, QB1.z); R.w = pair_relu_h2(PB1.w, QB1.w);
    *(uint4*)&h2s[buf][1][st1] = R;
    __syncthreads();

    int Tn = T + 128;
    if (Tn < NT) {
      int prA = Tn * 32 + pm, prB = (Tn + 64) * 32 + pm;
      int jA = jnA & (NPTS - 1), jB = jnB & (NPTS - 1);
      int nA = prA / 20, nB = prB / 20;
      PA0 = *(const uint4*)(pB + (size_t)jA * 128 + c2 * 16);
      PA1 = *(const uint4*)(pB + (size_t)jA * 128 + c2 * 16 + 8);
      QA0 = *(const uint4*)(qB + (size_t)nA * 128 + c2 * 16);
      QA1 = *(const uint4*)(qB + (size_t)nA * 128 + c2 * 16 + 8);
      PB0 = *(const uint4*)(pB + (size_t)jB * 128 + c2 * 16);
      PB1 = *(const uint4*)(pB + (size_t)jB * 128 + c2 * 16 + 8);
      QB0 = *(const uint4*)(qB + (size_t)nB * 128 + c2 * 16);
      QB1 = *(const uint4*)(qB + (size_t)nB * 128 + c2 * 16 + 8);
      int T2 = T + 256;
      if (T2 < NT) {
        jnA = idxB[T2 * 32 + pm];
        jnB = idxB[(T2 + 64) * 32 + pm];
      }
    }

    {
      v16f acc0 = {0.f}, acc1 = {0.f};
#pragma unroll
      for (int kk = 0; kk < 8; ++kk) {
        v8h a = *(const v8h*)&h2s[buf][0][col * 128 + (((kk * 2 + hi) ^ (col & 7)) * 8)];
        acc0 = __builtin_amdgcn_mfma_f32_32x32x16_f16(a, bfr0[kk], acc0, 0, 0, 0);
        acc1 = __builtin_amdgcn_mfma_f32_32x32x16_f16(a, bfr1[kk], acc1, 0, 0, 0);
      }
      float m0 = fmax3(acc0[0], acc0[1], acc0[2]);
      float m1 = fmax3(acc0[3], acc0[4], acc0[5]);
      float m2 = fmax3(acc0[6], acc0[7], acc0[8]);
      float m3 = fmax3(acc0[9], acc0[10], acc0[11]);
      float m4 = fmax3(acc0[12], acc0[13], acc0[14]);
      vmx0 = fmax3(fmax3(m0, m1, m2), fmax3(m3, m4, acc0[15]), vmx0);
      float n0 = fmax3(acc1[0], acc1[1], acc1[2]);
      float n1 = fmax3(acc1[3], acc1[4], acc1[5]);
      float n2 = fmax3(acc1[6], acc1[7], acc1[8]);
      float n3 = fmax3(acc1[9], acc1[10], acc1[11]);
      float n4 = fmax3(acc1[12], acc1[13], acc1[14]);
      vmx1 = fmax3(fmax3(n0, n1, n2), fmax3(n3, n4, acc1[15]), vmx1);
    }
    {
      v16f acc0 = {0.f}, acc1 = {0.f};
#pragma unroll
      for (int kk = 0; kk < 8; ++kk) {
        v8h a = *(const v8h*)&h2s[buf][1][col * 128 + (((kk * 2 + hi) ^ (col & 7)) * 8)];
        acc0 = __builtin_amdgcn_mfma_f32_32x32x16_f16(a, bfr0[kk], acc0, 0, 0, 0);
        acc1 = __builtin_amdgcn_mfma_f32_32x32x16_f16(a, bfr1[kk], acc1, 0, 0, 0);
      }
      float m0 = fmax3(acc0[0], acc0[1], acc0[2]);
      float m1 = fmax3(acc0[3], acc0[4], acc0[5]);
      float m2 = fmax3(acc0[6], acc0[7], acc0[8]);
      float m3 = fmax3(acc0[9], acc0[10], acc0[11]);
      float m4 = fmax3(acc0[12], acc0[13], acc0[14]);
      vmx0 = fmax3(fmax3(m0, m1, m2), fmax3(m3, m4, acc0[15]), vmx0);
      float n0 = fmax3(acc1[0], acc1[1], acc1[2]);
      float n1 = fmax3(acc1[3], acc1[4], acc1[5]);
      float n2 = fmax3(acc1[6], acc1[7], acc1[8]);
      float n3 = fmax3(acc1[9], acc1[10], acc1[11]);
      float n4 = fmax3(acc1[12], acc1[13], acc1[14]);
      vmx1 = fmax3(fmax3(n0, n1, n2), fmax3(n3, n4, acc1[15]), vmx1);
    }
    buf ^= 1;
  }

  float v0 = fmaxf(vmx0, __shfl_xor(vmx0, 32));
  float v1 = fmaxf(vmx1, __shfl_xor(vmx1, 32));
  if (hi == 0) {
    atomicMax(&H[b * 256 + wid * 64 + col], __float_as_int(v0));
    atomicMax(&H[b * 256 + wid * 64 + 32 + col], __float_as_int(v1));
  }
}

// ---------- K3: out = H @ fc_w^T + fc_b (one wave per output element) ----------
__global__ __launch_bounds__(64) void fc_kernel(const int* __restrict__ Hi,
                                                const float* __restrict__ fcw,
                                                const float* __restrict__ fcb,
                                                float* __restrict__ out) {
  int b = blockIdx.x / 10, r = blockIdx.x % 10;
  int lane = threadIdx.x;
  const float* Hb = (const float*)Hi + b * 256;
  float s = 0.f;
#pragma unroll
  for (int c = lane; c < 256; c += 64) s += Hb[c] * fcw[r * 256 + c];
#pragma unroll
  for (int m = 32; m > 0; m >>= 1) s += __shfl_xor(s, m);
  if (lane == 0) out[b * 10 + r] = s + fcb[r];
}

// ---------- launch ----------
extern "C" void kernel_launch(void* const* d_in, const int* in_sizes, int n_in,
                              void* d_out, int out_size, void* d_ws, size_t ws_size,
                              hipStream_t stream) {
  const float* x   = (const float*)d_in[0];
  const float* W1  = (const float*)d_in[1];
  const float* W2  = (const float*)d_in[2];
  const float* W3  = (const float*)d_in[3];
  const float* fcw = (const float*)d_in[4];
  const float* fcb = (const float*)d_in[5];
  float* out = (float*)d_out;
  char* ws = (char*)d_ws;

  // workspace layout (needs ~20 MB)
  int* H     = (int*)(ws + 4096);           // 16 KB (16x256 f32-as-int)
  int* idx   = (int*)(ws + 24576);          // 2.62 MB
  unsigned short* p = (unsigned short*)(ws + 3145728);   // 8.39 MB fp16
  unsigned short* q = (unsigned short*)(ws + 12582912);  // 8.39 MB fp16

  knn_kernel<<<BATCH * 32, 512, 0, stream>>>(x, idx, W1, W2, p, q, H);
  gemm_max_kernel<<<BATCH * 64, 256, 0, stream>>>(p, q, idx, W3, H);
  fc_kernel<<<BATCH * 10, 64, 0, stream>>>(H, fcw, fcb, out);
}